// Round 1
// baseline (146.974 us; speedup 1.0000x reference)
//
#include <hip/hip_runtime.h>
#include <hip/hip_bf16.h>

// NormPool2d: 3x3 reflect-padded window, output = mean - unbiased std.
// x: (16, 96, 224, 224) fp32 -> out same shape, fp32.
//
// Strategy: memory-bound streaming. Each thread owns one (plane, w) column
// and slides vertically over all H=224 rows, maintaining row-sum and
// row-sum-of-squares for a 3-row ring (only 2 live at a time plus the new
// one). 3 scalar loads per output (wm, w, wp), coalesced across the wave;
// the 3x horizontal overlap is absorbed by L1. HBM ideal = 616 MB -> ~98us.

#define NP_W 224
#define NP_H 224
#define NP_PLANES (16 * 96)

__global__ __launch_bounds__(256) void NormPool2d_kernel(
    const float* __restrict__ x, float* __restrict__ out) {
    const int W = NP_W, H = NP_H;
    int f = blockIdx.x * blockDim.x + threadIdx.x;  // f in [0, W*PLANES)
    if (f >= NP_W * NP_PLANES) return;
    int w = f % W;
    int plane = f / W;

    const float* __restrict__ xp = x + (size_t)plane * (H * W);
    float* __restrict__ op = out + (size_t)plane * (H * W) + w;

    // reflect padding in w (np.pad 'reflect': -1 -> 1, W -> W-2)
    int wm = (w == 0) ? 1 : w - 1;
    int wp = (w == W - 1) ? W - 2 : w + 1;

    // helper: row sums at physical row h
    auto rowvals = [&](int h, float& rs, float& rq) {
        const float* r = xp + (size_t)h * W;
        float a = r[wm];
        float b = r[w];
        float c = r[wp];
        rs = a + b + c;
        rq = a * a + b * b + c * c;
    };

    auto emit = [&](int h, float s, float q) {
        float mean = s * (1.f / 9.f);
        float var = (q - s * mean) * 0.125f;  // (ss - s^2/9) / 8, unbiased
        float sd = sqrtf(fmaxf(var, 0.f));
        op[(size_t)h * W] = mean - sd;
    };

    float a_s, a_q, b_s, b_q;
    rowvals(0, a_s, a_q);
    rowvals(1, b_s, b_q);

    // h = 0: rows {reflect(-1)=1, 0, 1} -> rs0 + 2*rs1
    emit(0, a_s + 2.f * b_s, a_q + 2.f * b_q);

    for (int h = 1; h < H - 1; ++h) {
        float c_s, c_q;
        rowvals(h + 1, c_s, c_q);
        emit(h, a_s + b_s + c_s, a_q + b_q + c_q);
        a_s = b_s; a_q = b_q;
        b_s = c_s; b_q = c_q;
    }

    // h = H-1: rows {H-2, H-1, reflect(H)=H-2} -> 2*rs[H-2] + rs[H-1]
    emit(H - 1, 2.f * a_s + b_s, 2.f * a_q + b_q);
}

extern "C" void kernel_launch(void* const* d_in, const int* in_sizes, int n_in,
                              void* d_out, int out_size, void* d_ws, size_t ws_size,
                              hipStream_t stream) {
    const float* x = (const float*)d_in[0];
    float* out = (float*)d_out;
    (void)in_sizes; (void)n_in; (void)out_size; (void)d_ws; (void)ws_size;

    const int total_cols = NP_W * NP_PLANES;  // 344064
    const int block = 256;
    const int grid = (total_cols + block - 1) / block;  // 1344
    NormPool2d_kernel<<<grid, block, 0, stream>>>(x, out);
}